// Round 9
// baseline (139.850 us; speedup 1.0000x reference)
//
#include <hip/hip_runtime.h>

// 3x3 conv, stride 1, pad 1, 4096x4096 fp32.
// Block = 256 threads covering a 1024-col x 32-row stripe, walked in 8 steps
// of 4 output rows. Register rotation for the 2 overlapping rows, prefetch
// distance 2, NT stores. R9 change: STEPS 4->8 — halves prologue cost per
// output row (18/16 -> 34/32 row-loads) and drain fraction (2/4 -> 2/8 steps).

#define H 4096
#define W 4096
#define CPT 4      // cols per thread
#define RPT 4      // rows per step
#define STEPS 8    // steps per block (stripe = 32 rows)
#define BLOCK 256

typedef float vfloat4 __attribute__((ext_vector_type(4)));

__device__ __forceinline__ void load_row(const float* __restrict__ x, int rr,
                                         int c, vfloat4& v, float& lf, float& rt) {
    if (rr >= 0 && rr < H) {
        const float* row = x + (size_t)rr * W + c;
        v = *(const vfloat4*)row;
        lf = (c > 0) ? row[-1] : 0.0f;
        rt = (c + CPT < W) ? row[CPT] : 0.0f;
    } else {
        v = (vfloat4)(0.f);
        lf = 0.f;
        rt = 0.f;
    }
}

__global__ __launch_bounds__(BLOCK, 4) void conv3x3_stripe(
    const float* __restrict__ x, const float* __restrict__ w9,
    const float* __restrict__ bias, float* __restrict__ out) {
    const int c = (blockIdx.x * BLOCK + threadIdx.x) * CPT;
    const int rbase = blockIdx.y * (STEPS * RPT);

    float wv[9];
#pragma unroll
    for (int i = 0; i < 9; ++i) wv[i] = w9[i];
    const float b = bias[0];

    // Current window: rows rbase-1 .. rbase+4.
    vfloat4 v[6];
    float lf[6], rt[6];
#pragma unroll
    for (int i = 0; i < 6; ++i) load_row(x, rbase - 1 + i, c, v[i], lf[i], rt[i]);

    // Prefetch stage 1: rows rbase+5 .. rbase+8 (for step 1).
    vfloat4 p[4];
    float plf[4], prt[4];
#pragma unroll
    for (int k = 0; k < 4; ++k) load_row(x, rbase + 5 + k, c, p[k], plf[k], prt[k]);

#pragma unroll
    for (int s = 0; s < STEPS; ++s) {
        const int r0 = rbase + s * RPT;

        // Prefetch stage 2: rows r0+9 .. r0+12 (for step s+2).
        vfloat4 q[4];
        float qlf[4], qrt[4];
        if (s < STEPS - 2) {
#pragma unroll
            for (int k = 0; k < 4; ++k)
                load_row(x, r0 + 9 + k, c, q[k], qlf[k], qrt[k]);
        }

        vfloat4 acc[RPT];
#pragma unroll
        for (int j = 0; j < RPT; ++j) acc[j] = (vfloat4)(b);

#pragma unroll
        for (int j = 0; j < RPT; ++j) {
#pragma unroll
            for (int dr = 0; dr < 3; ++dr) {
                const int i = j + dr;
                const float w0 = wv[dr * 3 + 0];
                const float w1 = wv[dr * 3 + 1];
                const float w2 = wv[dr * 3 + 2];
                acc[j].x = fmaf(w0, lf[i],  fmaf(w1, v[i].x, fmaf(w2, v[i].y, acc[j].x)));
                acc[j].y = fmaf(w0, v[i].x, fmaf(w1, v[i].y, fmaf(w2, v[i].z, acc[j].y)));
                acc[j].z = fmaf(w0, v[i].y, fmaf(w1, v[i].z, fmaf(w2, v[i].w, acc[j].z)));
                acc[j].w = fmaf(w0, v[i].z, fmaf(w1, v[i].w, fmaf(w2, rt[i],  acc[j].w)));
            }
        }

#pragma unroll
        for (int j = 0; j < RPT; ++j) {
            __builtin_nontemporal_store(acc[j],
                (vfloat4*)(out + (size_t)(r0 + j) * W + c));
        }

        // Rotate window and pipeline stages (full unroll -> pure renaming).
        if (s < STEPS - 1) {
            v[0] = v[4];  v[1] = v[5];
            lf[0] = lf[4]; lf[1] = lf[5];
            rt[0] = rt[4]; rt[1] = rt[5];
#pragma unroll
            for (int k = 0; k < 4; ++k) {
                v[2 + k] = p[k];
                lf[2 + k] = plf[k];
                rt[2 + k] = prt[k];
                p[k] = q[k];
                plf[k] = qlf[k];
                prt[k] = qrt[k];
            }
        }
    }
}

extern "C" void kernel_launch(void* const* d_in, const int* in_sizes, int n_in,
                              void* d_out, int out_size, void* d_ws, size_t ws_size,
                              hipStream_t stream) {
    const float* x = (const float*)d_in[0];
    const float* w = (const float*)d_in[1];
    const float* bias = (const float*)d_in[2];
    float* out = (float*)d_out;

    dim3 block(BLOCK, 1, 1);
    dim3 grid(W / (BLOCK * CPT), H / (STEPS * RPT), 1);
    conv3x3_stripe<<<grid, block, 0, stream>>>(x, w, bias, out);
}

// Round 10
// 115.682 us; speedup vs baseline: 1.2089x; 1.2089x over previous
//
#include <hip/hip_runtime.h>

// 3x3 conv, stride 1, pad 1, 4096x4096 fp32.  (R7 configuration — best: ~27 µs)
// Block = 256 threads covering a 1024-col x 16-row stripe, walked in 4 steps
// of 4 output rows. Register rotation for the 2 overlapping rows; NT stores;
// prefetch distance 2 (rows for step s+2 issued during step s).
// Do NOT raise STEPS (R9: allocator picked 64 VGPR, spilled, 2x slower) or
// CPT (R8: ~190 VGPR state, occupancy drop, 1.3x slower).

#define H 4096
#define W 4096
#define CPT 4      // cols per thread
#define RPT 4      // rows per step
#define STEPS 4    // steps per block (stripe = 16 rows)
#define BLOCK 256

typedef float vfloat4 __attribute__((ext_vector_type(4)));

__device__ __forceinline__ void load_row(const float* __restrict__ x, int rr,
                                         int c, vfloat4& v, float& lf, float& rt) {
    if (rr >= 0 && rr < H) {
        const float* row = x + (size_t)rr * W + c;
        v = *(const vfloat4*)row;
        lf = (c > 0) ? row[-1] : 0.0f;
        rt = (c + CPT < W) ? row[CPT] : 0.0f;
    } else {
        v = (vfloat4)(0.f);
        lf = 0.f;
        rt = 0.f;
    }
}

__global__ __launch_bounds__(BLOCK, 4) void conv3x3_stripe(
    const float* __restrict__ x, const float* __restrict__ w9,
    const float* __restrict__ bias, float* __restrict__ out) {
    const int c = (blockIdx.x * BLOCK + threadIdx.x) * CPT;
    const int rbase = blockIdx.y * (STEPS * RPT);

    float wv[9];
#pragma unroll
    for (int i = 0; i < 9; ++i) wv[i] = w9[i];
    const float b = bias[0];

    // Current window: rows rbase-1 .. rbase+4.
    vfloat4 v[6];
    float lf[6], rt[6];
#pragma unroll
    for (int i = 0; i < 6; ++i) load_row(x, rbase - 1 + i, c, v[i], lf[i], rt[i]);

    // Prefetch stage 1: rows rbase+5 .. rbase+8 (for step 1).
    vfloat4 p[4];
    float plf[4], prt[4];
#pragma unroll
    for (int k = 0; k < 4; ++k) load_row(x, rbase + 5 + k, c, p[k], plf[k], prt[k]);

#pragma unroll
    for (int s = 0; s < STEPS; ++s) {
        const int r0 = rbase + s * RPT;

        // Prefetch stage 2: rows r0+9 .. r0+12 (for step s+2).
        vfloat4 q[4];
        float qlf[4], qrt[4];
        if (s < STEPS - 2) {
#pragma unroll
            for (int k = 0; k < 4; ++k)
                load_row(x, r0 + 9 + k, c, q[k], qlf[k], qrt[k]);
        }

        vfloat4 acc[RPT];
#pragma unroll
        for (int j = 0; j < RPT; ++j) acc[j] = (vfloat4)(b);

#pragma unroll
        for (int j = 0; j < RPT; ++j) {
#pragma unroll
            for (int dr = 0; dr < 3; ++dr) {
                const int i = j + dr;
                const float w0 = wv[dr * 3 + 0];
                const float w1 = wv[dr * 3 + 1];
                const float w2 = wv[dr * 3 + 2];
                acc[j].x = fmaf(w0, lf[i],  fmaf(w1, v[i].x, fmaf(w2, v[i].y, acc[j].x)));
                acc[j].y = fmaf(w0, v[i].x, fmaf(w1, v[i].y, fmaf(w2, v[i].z, acc[j].y)));
                acc[j].z = fmaf(w0, v[i].y, fmaf(w1, v[i].z, fmaf(w2, v[i].w, acc[j].z)));
                acc[j].w = fmaf(w0, v[i].z, fmaf(w1, v[i].w, fmaf(w2, rt[i],  acc[j].w)));
            }
        }

#pragma unroll
        for (int j = 0; j < RPT; ++j) {
            __builtin_nontemporal_store(acc[j],
                (vfloat4*)(out + (size_t)(r0 + j) * W + c));
        }

        // Rotate window and pipeline stages (full unroll -> pure renaming).
        if (s < STEPS - 1) {
            v[0] = v[4];  v[1] = v[5];
            lf[0] = lf[4]; lf[1] = lf[5];
            rt[0] = rt[4]; rt[1] = rt[5];
#pragma unroll
            for (int k = 0; k < 4; ++k) {
                v[2 + k] = p[k];
                lf[2 + k] = plf[k];
                rt[2 + k] = prt[k];
                p[k] = q[k];
                plf[k] = qlf[k];
                prt[k] = qrt[k];
            }
        }
    }
}

extern "C" void kernel_launch(void* const* d_in, const int* in_sizes, int n_in,
                              void* d_out, int out_size, void* d_ws, size_t ws_size,
                              hipStream_t stream) {
    const float* x = (const float*)d_in[0];
    const float* w = (const float*)d_in[1];
    const float* bias = (const float*)d_in[2];
    float* out = (float*)d_out;

    dim3 block(BLOCK, 1, 1);
    dim3 grid(W / (BLOCK * CPT), H / (STEPS * RPT), 1);
    conv3x3_stripe<<<grid, block, 0, stream>>>(x, w, bias, out);
}